// Round 1
// baseline (677.860 us; speedup 1.0000x reference)
//
#include <hip/hip_runtime.h>

// RoutingCapsule: x(16,2048,16) fp32, W(1,2048,64,32,16) fp32, bias(64,32) fp32
// -> v(16,64,32) fp32.   Routing collapses (b_logits additive from 0):
//   s0 = (1/64) sum_i u ; v0 = squash(s0+bias)
//   pass1: c1 = softmax_o(u.v0)      ; s1 = sum_i c1*u
//   pass2: c2 = softmax_o(u.(v0+v1)) ; out = squash(sum_i c2*u + bias)
//
// R7 (this round): top-5 rocprof dispatches are all 1-GiB harness poison fills
// (~160us @84% peak) -> every kernel of ours is <158us; loss is distributed.
// Structural fixes: (a) k_route rebuilt wave-autonomous (64-thr blocks, 16 i
// per wave, register acc, no LDS/syncthreads, grid 2048 = exactly 8 blocks/CU,
// single scheduling round, no tail; old version had 3 blocks/CU resident for a
// 4-blocks/CU workload -> 25% of blocks in a straggler round at 1/3 occupancy
// plus a pointless 32KB LDS reduce). (b) k_uhat pinned 4 blocks/CU via
// __launch_bounds__(256,4). (c) W loads nontemporal so u (exactly 256 MiB =
// LLC size) can stay LLC-resident for the two route re-reads. (d) rcp instead
// of divide in softmax. (e) part2 overlays part0 -> ws usage ~319 MB as before.
#define B_ 16
#define I_ 2048
#define OD_ 2048
#define EPSQ 1e-9f

typedef float v4f __attribute__((ext_vector_type(4)));

__device__ __forceinline__ float squashf(float s) {
  float sq = s * s;
  return sq / (1.0f + sq) * s * rsqrtf(sq + EPSQ);
}

// ---------------------------------------------------------------------------
// K1: u[b,i,od] = sum_p x[b,i,p]*W[i,od,p]  (fp32), plus per-block s0 partials
// (register-accumulated over the block's 8 i, no extra u read).
// grid=1024: bx&3 = od-quarter, bx>>2 = i-chunk ic. Thread owns od-pair pr.
// part0[ic][b][od] : 256*16*2048 fp32 = 32 MB.
// launch_bounds(256,4): 4 blocks/CU resident -> grid drains in ONE round.
// ---------------------------------------------------------------------------
__global__ __launch_bounds__(256, 4) void k_uhat(
    const float* __restrict__ x, const float* __restrict__ W,
    float* __restrict__ u, float* __restrict__ part0)
{
  const int t = threadIdx.x;
  const int q = blockIdx.x & 3;
  const int ic = blockIdx.x >> 2;
  const int i0 = ic * 8;
  const int pr = q * 256 + t;  // od-pair 0..1023

  float s0a[B_], s0b[B_];
#pragma unroll
  for (int b = 0; b < B_; ++b) { s0a[b] = 0.f; s0b[b] = 0.f; }

  for (int ii = 0; ii < 8; ++ii) {
    const int i = i0 + ii;
    const v4f* wp = (const v4f*)(W + (size_t)(i * OD_ + pr * 2) * 16);
    v4f w[8];
#pragma unroll
    for (int k = 0; k < 8; ++k) w[k] = __builtin_nontemporal_load(wp + k);

#pragma unroll
    for (int b = 0; b < B_; ++b) {
      const v4f* xp = (const v4f*)(x + (size_t)(b * I_ + i) * 16);
      float u0 = 0.f, u1 = 0.f;
#pragma unroll
      for (int qq = 0; qq < 4; ++qq) {
        v4f xq = xp[qq];
        v4f wa = w[qq], wb = w[qq + 4];
        u0 += xq.x * wa.x + xq.y * wa.y + xq.z * wa.z + xq.w * wa.w;
        u1 += xq.x * wb.x + xq.y * wb.y + xq.z * wb.z + xq.w * wb.w;
      }
      float2 uv; uv.x = u0; uv.y = u1;
      *(float2*)(u + (size_t)(b * I_ + i) * OD_ + pr * 2) = uv;
      s0a[b] += u0; s0b[b] += u1;
    }
  }
#pragma unroll
  for (int b = 0; b < B_; ++b) {
    float2 sv; sv.x = s0a[b]; sv.y = s0b[b];
    ((float2*)part0)[(size_t)(ic * B_ + b) * 1024 + pr] = sv;
  }
}

// ---------------------------------------------------------------------------
// K2: s0_raw[b,od] = sum_ic part0[ic][b][od].  grid=128: b=bx>>3, od block.
// ---------------------------------------------------------------------------
__global__ __launch_bounds__(256) void k_s0red(
    const float* __restrict__ part0, float* __restrict__ s0)
{
  const int b = blockIdx.x >> 3;
  const int od = (blockIdx.x & 7) * 256 + threadIdx.x;
  float a = 0.f;
  const float* p = part0 + (size_t)b * OD_ + od;
#pragma unroll 8
  for (int ic = 0; ic < 256; ++ic) a += p[(size_t)ic * B_ * OD_];
  s0[b * OD_ + od] = a;
}

// ---------------------------------------------------------------------------
// K3: one routing pass, WAVE-AUTONOMOUS. grid=2048 blocks x 64 threads.
// lane = o; block = (b, i-group g of 16 rows). vv = squash(sA*scaleA+bias)
// [+ squash(sB+bias)]. Per i: logit = sum_d u*vv; 64-lane softmax over o;
// acc += c*u in registers. Block writes its 2048-float partial directly.
// No LDS, no syncthreads, no atomics. 2048 blocks = exactly 8 blocks/CU ->
// single round, zero tail.  part[b*128+g][od] : 16*128*2048 fp32 = 16 MB.
// ---------------------------------------------------------------------------
__global__ __launch_bounds__(64, 2) void k_route(
    const float* __restrict__ u,
    const float* __restrict__ sA, float scaleA,
    const float* __restrict__ sB,  // may be null
    const float* __restrict__ bias,
    float* __restrict__ part)
{
  const int o = threadIdx.x;           // 0..63
  const int b = blockIdx.x >> 7;       // 16 b
  const int g = blockIdx.x & 127;      // 128 i-groups
  const int i0 = g * 16;

  v4f vv[8], acc[8];
  {
    const float* sa = sA + b * OD_ + o * 32;
    const float* sb = sB ? sB + b * OD_ + o * 32 : nullptr;
    const float* bp = bias + o * 32;
#pragma unroll
    for (int qq = 0; qq < 8; ++qq) {
#pragma unroll
      for (int j = 0; j < 4; ++j) {
        float bs = bp[qq * 4 + j];
        float val = squashf(sa[qq * 4 + j] * scaleA + bs);
        if (sb) val += squashf(sb[qq * 4 + j] + bs);
        vv[qq][j] = val;
      }
      v4f z = {0.f, 0.f, 0.f, 0.f};
      acc[qq] = z;
    }
  }

  for (int ii = 0; ii < 16; ++ii) {
    const int i = i0 + ii;
    const v4f* up = (const v4f*)(u + (size_t)(b * I_ + i) * OD_ + o * 32);
    v4f r[8];
#pragma unroll
    for (int qq = 0; qq < 8; ++qq) r[qq] = up[qq];

    float logit = 0.f;
#pragma unroll
    for (int qq = 0; qq < 8; ++qq)
#pragma unroll
      for (int j = 0; j < 4; ++j)
        logit = fmaf(r[qq][j], vv[qq][j], logit);

    float m = logit;
#pragma unroll
    for (int off = 32; off > 0; off >>= 1) m = fmaxf(m, __shfl_xor(m, off, 64));
    float e = __expf(logit - m);
    float sm = e;
#pragma unroll
    for (int off = 32; off > 0; off >>= 1) sm += __shfl_xor(sm, off, 64);
    float c = e * __builtin_amdgcn_rcpf(sm);

#pragma unroll
    for (int qq = 0; qq < 8; ++qq)
#pragma unroll
      for (int j = 0; j < 4; ++j)
        acc[qq][j] = fmaf(c, r[qq][j], acc[qq][j]);
  }

  v4f* pp = (v4f*)(part + (size_t)(b * 128 + g) * OD_ + o * 32);
#pragma unroll
  for (int qq = 0; qq < 8; ++qq) pp[qq] = acc[qq];
}

// ---------------------------------------------------------------------------
// K4: s1[b,od] = sum_g part[(b*128+g)][od].  grid=128.
// ---------------------------------------------------------------------------
__global__ __launch_bounds__(256) void k_s1red(
    const float* __restrict__ part, float* __restrict__ s1)
{
  const int b = blockIdx.x >> 3;
  const int od = (blockIdx.x & 7) * 256 + threadIdx.x;
  float a = 0.f;
  const float* p = part + (size_t)b * 128 * OD_ + od;
#pragma unroll 8
  for (int g = 0; g < 128; ++g) a += p[(size_t)g * OD_];
  s1[b * OD_ + od] = a;
}

// ---------------------------------------------------------------------------
// K5: out[b,od] = squash(sum_g part2 + bias).  grid=128.
// ---------------------------------------------------------------------------
__global__ __launch_bounds__(256) void k_outred(
    const float* __restrict__ part, const float* __restrict__ bias,
    float* __restrict__ out)
{
  const int b = blockIdx.x >> 3;
  const int od = (blockIdx.x & 7) * 256 + threadIdx.x;
  float a = 0.f;
  const float* p = part + (size_t)b * 128 * OD_ + od;
#pragma unroll 8
  for (int g = 0; g < 128; ++g) a += p[(size_t)g * OD_];
  out[b * OD_ + od] = squashf(a + bias[od]);
}

extern "C" void kernel_launch(void* const* d_in, const int* in_sizes, int n_in,
                              void* d_out, int out_size, void* d_ws, size_t ws_size,
                              hipStream_t stream) {
  const float* x = (const float*)d_in[0];
  const float* W = (const float*)d_in[1];
  const float* bias = (const float*)d_in[2];
  float* out = (float*)d_out;

  char* ws = (char*)d_ws;
  float* u_ws  = (float*)ws;                          // 256 MB fp32 u_hat
  float* part0 = (float*)(ws + 268435456ull);         // 32 MB s0 partials
  float* part1 = (float*)(ws + 301989888ull);         // 16 MB route partials
  float* part2 = part0;                               // reuse: part0 dead after K2
  float* s0    = (float*)(ws + 318767104ull);         // 128 KB
  float* s1    = s0 + 32768;                          // 128 KB

  k_uhat <<<dim3(1024), dim3(256), 0, stream>>>(x, W, u_ws, part0);
  k_s0red<<<dim3(128),  dim3(256), 0, stream>>>(part0, s0);
  // pass1: v0 = squash(s0/64 + bias)
  k_route<<<dim3(2048), dim3(64),  0, stream>>>(u_ws, s0, 1.0f / 64.0f, nullptr, bias, part1);
  k_s1red<<<dim3(128),  dim3(256), 0, stream>>>(part1, s1);
  // pass2: vv = squash(s0/64+bias) + squash(s1+bias)
  k_route<<<dim3(2048), dim3(64),  0, stream>>>(u_ws, s0, 1.0f / 64.0f, s1, bias, part2);
  k_outred<<<dim3(128), dim3(256), 0, stream>>>(part2, bias, out);
}